// Round 4
// baseline (470.957 us; speedup 1.0000x reference)
//
#include <hip/hip_runtime.h>
#include <hip/hip_bf16.h>
#include <cstdint>

#define T_TOK 2048
#define HD 2048
#define ID 1408
#define NE 16
#define TOPK 6

#define BM 256
#define BN 64
#define BK 64

typedef __bf16 bf16x8 __attribute__((ext_vector_type(8)));
typedef float f32x4 __attribute__((ext_vector_type(4)));

typedef const __attribute__((address_space(1))) void* gas1_t;
typedef __attribute__((address_space(3))) void* las3_t;
#define GLDS16(g, l) __builtin_amdgcn_global_load_lds((gas1_t)(g), (las3_t)(l), 16, 0, 0)

// --- small kernels -----------------------------------------------------

__global__ void k_combine(const int* __restrict__ idx, const float* __restrict__ w,
                          float* __restrict__ combine) {
    int t = blockIdx.x * blockDim.x + threadIdx.x;
    if (t >= T_TOK) return;
    int ie[TOPK];
    float fw[TOPK];
#pragma unroll
    for (int k = 0; k < TOPK; k++) { ie[k] = idx[t * TOPK + k]; fw[k] = w[t * TOPK + k]; }
#pragma unroll
    for (int e = 0; e < NE; e++) {
        float s = 0.f;
#pragma unroll
        for (int k = 0; k < TOPK; k++) if (ie[k] == e) s += fw[k];
        combine[t * NE + e] = s;
    }
}

__global__ void k_lists(const float* __restrict__ combine, int* __restrict__ counts,
                        int* __restrict__ tok, float* __restrict__ wts) {
    int t = blockIdx.x * blockDim.x + threadIdx.x;
    if (t >= T_TOK) return;
    for (int e = 0; e < NE; e++) {
        float c = combine[t * NE + e];
        if (c != 0.0f) {
            int p = atomicAdd(&counts[e], 1);
            tok[e * T_TOK + p] = t;
            wts[e * T_TOK + p] = c;
        }
    }
}

__global__ void k_cvt(const float* __restrict__ x, __bf16* __restrict__ xb) {
    int i = (blockIdx.x * 256 + threadIdx.x) * 8;
    float4 a = *(const float4*)(x + i);
    float4 b = *(const float4*)(x + i + 4);
    bf16x8 o;
    o[0] = (__bf16)a.x; o[1] = (__bf16)a.y; o[2] = (__bf16)a.z; o[3] = (__bf16)a.w;
    o[4] = (__bf16)b.x; o[5] = (__bf16)b.y; o[6] = (__bf16)b.z; o[7] = (__bf16)b.w;
    *(bf16x8*)(xb + i) = o;
}

// --- LDS helpers -------------------------------------------------------

__device__ __forceinline__ int swz(int row, int cb) {
    // rows are 128B; XOR-swizzle bits 4..6 by row&7 (Guideline 4)
    return row * 128 + (cb ^ ((row & 7) << 4));
}

__device__ __forceinline__ bf16x8 ldfrag(const __bf16* base, int row, int cb) {
    return *(const bf16x8*)((const char*)base + swz(row, cb));
}

// 8 fp32 (in regs) -> 8 bf16 -> one swizzled 16B LDS store
__device__ __forceinline__ void stage8v(char* lds, int row, int cb, float4 f0, float4 f1) {
    bf16x8 o;
    o[0] = (__bf16)f0.x; o[1] = (__bf16)f0.y; o[2] = (__bf16)f0.z; o[3] = (__bf16)f0.w;
    o[4] = (__bf16)f1.x; o[5] = (__bf16)f1.y; o[6] = (__bf16)f1.z; o[7] = (__bf16)f1.w;
    *(bf16x8*)(lds + swz(row, cb)) = o;
}

// --- GEMM1: act = silu(X@Gg^T) * (X@Gu^T)  ------------------------------
// grid.x = e*22 + n (same (n,e) => same XCD for all m); grid.y = m
// 1-deep pipeline: A dbuf via global_load_lds, B reg-prefetch; barrier drain
// at end of MFMA phase doubles as the pipeline wait.

__global__ __launch_bounds__(512, 4) void k_gemm1(
    const __bf16* __restrict__ Xb, const float* __restrict__ gup,
    const int* __restrict__ counts, const int* __restrict__ tok,
    __bf16* __restrict__ act) {
    int x = blockIdx.x;
    int e = x / 22;
    int n0 = (x % 22) * BN;
    int cnt = counts[e];
    int m0 = blockIdx.y * BM;
    if (m0 >= cnt) return;

    __shared__ __align__(16) __bf16 sA[2][BM * BK];
    __shared__ __align__(16) __bf16 sBg[BN * BK];
    __shared__ __align__(16) __bf16 sBu[BN * BK];

    int tid = threadIdx.x;
    int lane = tid & 63;
    int wid = tid >> 6;

    // A staging: wave w owns rows [32w, 32w+32). Linear LDS dest via glds;
    // per-lane global source column pre-swizzled so swizzled reads decode it.
    const __bf16* pA[4];
    int csw = ((lane & 7) ^ ((lane >> 3) & 7)) * 8;
#pragma unroll
    for (int j = 0; j < 4; j++) {
        int r = 32 * wid + 8 * j + (lane >> 3);
        int g = m0 + r;
        if (g >= cnt) g = cnt - 1;
        pA[j] = Xb + (size_t)tok[e * T_TOK + g] * HD + csw;
    }

    // B staging roles: 64 rows x 8 chunks of 8 floats (per matrix)
    int br = tid >> 3, bc = tid & 7;
    const float* gbase = gup + (size_t)e * (2 * ID) * HD;
    const float* bgSrc = gbase + (size_t)(n0 + br) * HD + bc * 8;
    const float* buSrc = gbase + (size_t)(ID + n0 + br) * HD + bc * 8;

    int wm = wid >> 1, wn = wid & 1;           // 4x2 waves over 256x64
    int l15 = lane & 15, lh = lane >> 4;

    f32x4 accg[4][2] = {};
    f32x4 accu[4][2] = {};

    // prologue: tile 0 -> regs (B) + sA[0] (A)
    float4 g0 = ((const float4*)bgSrc)[0], g1 = ((const float4*)bgSrc)[1];
    float4 u0 = ((const float4*)buSrc)[0], u1 = ((const float4*)buSrc)[1];
#pragma unroll
    for (int j = 0; j < 4; j++)
        GLDS16(pA[j], &sA[0][(32 * wid + 8 * j) * BK]);
    __syncthreads();   // drains tile-0 loads

    const int NT = HD / BK;
    for (int k = 0; k < NT; k++) {
        int cur = k & 1;
        // ds_write B(k) from regs (no vm dependency -- drained at last barrier)
        stage8v((char*)sBg, br, bc * 16, g0, g1);
        stage8v((char*)sBu, br, bc * 16, u0, u1);
        __syncthreads();   // cheap: lgkm only, nothing vm-outstanding

        // issue tile k+1 (fills the MFMA phase below)
        if (k + 1 < NT) {
            int k0 = (k + 1) * BK;
#pragma unroll
            for (int j = 0; j < 4; j++)
                GLDS16(pA[j] + k0, &sA[cur ^ 1][(32 * wid + 8 * j) * BK]);
            const float* bg = bgSrc + k0;
            const float* bu = buSrc + k0;
            g0 = ((const float4*)bg)[0]; g1 = ((const float4*)bg)[1];
            u0 = ((const float4*)bu)[0]; u1 = ((const float4*)bu)[1];
        }

        // MFMA phase on tile k
        const __bf16* sAc = sA[cur];
#pragma unroll
        for (int kk = 0; kk < 2; kk++) {
            int cb = kk * 64 + lh * 16;
            bf16x8 a[4];
#pragma unroll
            for (int fm = 0; fm < 4; fm++)
                a[fm] = ldfrag(sAc, wm * 64 + fm * 16 + l15, cb);
#pragma unroll
            for (int fn = 0; fn < 2; fn++) {
                bf16x8 bg = ldfrag(sBg, wn * 32 + fn * 16 + l15, cb);
                bf16x8 bu = ldfrag(sBu, wn * 32 + fn * 16 + l15, cb);
#pragma unroll
                for (int fm = 0; fm < 4; fm++) {
                    accg[fm][fn] = __builtin_amdgcn_mfma_f32_16x16x32_bf16(a[fm], bg, accg[fm][fn], 0, 0, 0);
                    accu[fm][fn] = __builtin_amdgcn_mfma_f32_16x16x32_bf16(a[fm], bu, accu[fm][fn], 0, 0, 0);
                }
            }
        }
        __syncthreads();   // pipeline wait: drains A(k+1) glds + B(k+1) reg loads
    }

    // epilogue: silu(gate)*up -> act (bf16)
#pragma unroll
    for (int fm = 0; fm < 4; fm++) {
#pragma unroll
        for (int fn = 0; fn < 2; fn++) {
#pragma unroll
            for (int j = 0; j < 4; j++) {
                int mloc = wm * 64 + fm * 16 + lh * 4 + j;
                int g = m0 + mloc;
                if (g < cnt) {
                    float gv = accg[fm][fn][j];
                    float uv = accu[fm][fn][j];
                    float sv = gv * (1.0f / (1.0f + __expf(-gv)));
                    int n = n0 + wn * 32 + fn * 16 + l15;
                    act[((size_t)e * T_TOK + g) * ID + n] = (__bf16)(sv * uv);
                }
            }
        }
    }
}

// --- GEMM2: out[tok] += (act @ Dn^T) * wt  (fp32 atomic scatter) --------
// grid.x = e*32 + n; grid.y = m; same pipeline as gemm1.

__global__ __launch_bounds__(512, 4) void k_gemm2(
    const __bf16* __restrict__ act, const float* __restrict__ dn,
    const int* __restrict__ counts, const int* __restrict__ tok,
    const float* __restrict__ wts, float* __restrict__ out) {
    int x = blockIdx.x;
    int e = x >> 5;
    int n0 = (x & 31) * BN;
    int cnt = counts[e];
    int m0 = blockIdx.y * BM;
    if (m0 >= cnt) return;

    __shared__ __align__(16) __bf16 sA[2][BM * BK];
    __shared__ __align__(16) __bf16 sB[BN * BK];
    __shared__ int tokLds[BM];
    __shared__ float wtLds[BM];

    int tid = threadIdx.x;
    if (tid < BM) {
        int g = m0 + tid;
        bool v = g < cnt;
        tokLds[tid] = v ? tok[e * T_TOK + g] : 0;
        wtLds[tid] = v ? wts[e * T_TOK + g] : 0.f;
    }

    int lane = tid & 63;
    int wid = tid >> 6;

    const __bf16* pA[4];
    int csw = ((lane & 7) ^ ((lane >> 3) & 7)) * 8;
#pragma unroll
    for (int j = 0; j < 4; j++) {
        int r = 32 * wid + 8 * j + (lane >> 3);
        pA[j] = act + ((size_t)e * T_TOK + m0 + r) * ID + csw;
    }

    int br = tid >> 3, bc = tid & 7;
    const float* bSrc = dn + (size_t)e * HD * ID + (size_t)(n0 + br) * ID + bc * 8;

    int wm = wid >> 1, wn = wid & 1;
    int l15 = lane & 15, lh = lane >> 4;

    f32x4 acc[4][2] = {};

    float4 b0 = ((const float4*)bSrc)[0], b1 = ((const float4*)bSrc)[1];
#pragma unroll
    for (int j = 0; j < 4; j++)
        GLDS16(pA[j], &sA[0][(32 * wid + 8 * j) * BK]);
    __syncthreads();

    const int NT = ID / BK;
    for (int k = 0; k < NT; k++) {
        int cur = k & 1;
        stage8v((char*)sB, br, bc * 16, b0, b1);
        __syncthreads();   // cheap: lgkm only

        if (k + 1 < NT) {
            int k0 = (k + 1) * BK;
#pragma unroll
            for (int j = 0; j < 4; j++)
                GLDS16(pA[j] + k0, &sA[cur ^ 1][(32 * wid + 8 * j) * BK]);
            const float* bs = bSrc + k0;
            b0 = ((const float4*)bs)[0]; b1 = ((const float4*)bs)[1];
        }

        const __bf16* sAc = sA[cur];
#pragma unroll
        for (int kk = 0; kk < 2; kk++) {
            int cb = kk * 64 + lh * 16;
            bf16x8 a[4];
#pragma unroll
            for (int fm = 0; fm < 4; fm++)
                a[fm] = ldfrag(sAc, wm * 64 + fm * 16 + l15, cb);
#pragma unroll
            for (int fn = 0; fn < 2; fn++) {
                bf16x8 b = ldfrag(sB, wn * 32 + fn * 16 + l15, cb);
#pragma unroll
                for (int fm = 0; fm < 4; fm++)
                    acc[fm][fn] = __builtin_amdgcn_mfma_f32_16x16x32_bf16(a[fm], b, acc[fm][fn], 0, 0, 0);
            }
        }
        __syncthreads();   // pipeline wait
    }

#pragma unroll
    for (int fm = 0; fm < 4; fm++) {
#pragma unroll
        for (int fn = 0; fn < 2; fn++) {
#pragma unroll
            for (int j = 0; j < 4; j++) {
                int mloc = wm * 64 + fm * 16 + lh * 4 + j;
                int g = m0 + mloc;
                if (g < cnt) {
                    float v = acc[fm][fn][j] * wtLds[mloc];
                    int n = n0 + wn * 32 + fn * 16 + l15;
                    atomicAdd(&out[(size_t)tokLds[mloc] * HD + n], v);
                }
            }
        }
    }
}

// --- launch --------------------------------------------------------------

extern "C" void kernel_launch(void* const* d_in, const int* in_sizes, int n_in,
                              void* d_out, int out_size, void* d_ws, size_t ws_size,
                              hipStream_t stream) {
    const float* hs = (const float*)d_in[0];
    const int* tki = (const int*)d_in[1];
    const float* tkw = (const float*)d_in[2];
    const float* gup = (const float*)d_in[3];
    const float* dnp = (const float*)d_in[4];
    float* out = (float*)d_out;

    char* p = (char*)d_ws;
    int* counts = (int*)p;      p += 256;
    float* combine = (float*)p; p += (size_t)T_TOK * NE * 4;
    int* tok = (int*)p;         p += (size_t)NE * T_TOK * 4;
    float* wts = (float*)p;     p += (size_t)NE * T_TOK * 4;
    __bf16* Xb = (__bf16*)p;    p += (size_t)T_TOK * HD * 2;
    __bf16* act = (__bf16*)p;   // NE*T_TOK*ID*2 = 92MB

    hipMemsetAsync(counts, 0, 256, stream);
    hipMemsetAsync(d_out, 0, (size_t)T_TOK * HD * 4, stream);
    k_combine<<<T_TOK / 256, 256, 0, stream>>>(tki, tkw, combine);
    k_lists<<<T_TOK / 256, 256, 0, stream>>>(combine, counts, tok, wts);
    k_cvt<<<(T_TOK * HD / 8) / 256, 256, 0, stream>>>(hs, Xb);
    k_gemm1<<<dim3(22 * NE, T_TOK / BM), 512, 0, stream>>>(Xb, gup, counts, tok, act);
    k_gemm2<<<dim3(32 * NE, T_TOK / BM), 512, 0, stream>>>(act, dnp, counts, tok, wts, out);
}